// Round 14
// baseline (181.724 us; speedup 1.0000x reference)
//
#include <hip/hip_runtime.h>
#include <math.h>

#define THREADS 256
#define S1THREADS 512
#define BSHIFT 9              // 512 dsts per bucket
#define BSIZE (1 << BSHIFT)
#define PASS1_CHUNK 4096
#define SRC_BITS 17           // n < 131072
#define S2CAP 12288           // sort2 LDS pair-stage capacity (48KB)

typedef unsigned int u32;
typedef unsigned short u16;
typedef __attribute__((ext_vector_type(8))) short short8v;   // 8 bf16 (4 VGPR)
typedef __attribute__((ext_vector_type(4))) float float4v;   // MFMA acc

__device__ __forceinline__ u16 f2bf(float f) {      // RNE fp32 -> bf16
    u32 u = __float_as_uint(f);
    u = (u + 0x7fffu + ((u >> 16) & 1u)) >> 16;
    return (u16)u;
}
__device__ __forceinline__ float bf_lo(u32 u) { return __uint_as_float(u << 16); }
__device__ __forceinline__ float bf_hi(u32 u) { return __uint_as_float(u & 0xffff0000u); }

// ---------------- phase 1: per-block bucket histogram -> hmat[blk][bucket] ----

__global__ __launch_bounds__(S1THREADS) void hist_kernel(
    const int* __restrict__ dst, int* __restrict__ hmat, int e, int nbuck, int valn)
{
    __shared__ int hist[BSIZE];
    const int tid = threadIdx.x;
    const int c0  = blockIdx.x * PASS1_CHUNK;
    for (int i = tid; i < nbuck; i += S1THREADS) hist[i] = 0;
    __syncthreads();
    if (valn) {   // 16B-aligned dst, 4 edges per iter
        for (int i = tid * 4; i < PASS1_CHUNK; i += S1THREADS * 4) {
            int idx = c0 + i;
            if (idx + 3 < e) {
                int4 dv = *(const int4*)(dst + idx);
                atomicAdd(&hist[dv.x >> BSHIFT], 1);
                atomicAdd(&hist[dv.y >> BSHIFT], 1);
                atomicAdd(&hist[dv.z >> BSHIFT], 1);
                atomicAdd(&hist[dv.w >> BSHIFT], 1);
            } else {
                for (int k = 0; k < 4; ++k)
                    if (idx + k < e) atomicAdd(&hist[dst[idx + k] >> BSHIFT], 1);
            }
        }
    } else {
        for (int i = tid; i < PASS1_CHUNK; i += S1THREADS) {
            int idx = c0 + i;
            if (idx < e) atomicAdd(&hist[dst[idx] >> BSHIFT], 1);
        }
    }
    __syncthreads();
    for (int b = tid; b < nbuck; b += S1THREADS)
        hmat[blockIdx.x * nbuck + b] = hist[b];
}

// ---------------- phase 2: column scan of hmat -> bmat (relative), bcnt -------

__global__ __launch_bounds__(THREADS) void colscan_kernel(
    const int* __restrict__ hmat, int* __restrict__ bmat,
    int* __restrict__ bcnt, int nblk, int nbuck)
{
    __shared__ int s[THREADS];
    const int b = blockIdx.x, tid = threadIdx.x;
    int run = 0;
    for (int t0 = 0; t0 < nblk; t0 += THREADS) {
        int idx = t0 + tid;
        int v = (idx < nblk) ? hmat[idx * nbuck + b] : 0;
        s[tid] = v;
        __syncthreads();
        for (int off = 1; off < THREADS; off <<= 1) {
            int t = (tid >= off) ? s[tid - off] : 0;
            __syncthreads();
            s[tid] += t;
            __syncthreads();
        }
        if (idx < nblk) bmat[idx * nbuck + b] = run + s[tid] - v;
        run += s[THREADS - 1];
        __syncthreads();
    }
    if (tid == 0) bcnt[b] = run;
}

// ---------------- phase 3: scatter packed (ld<<17|src) into bucket regions ----

__global__ __launch_bounds__(S1THREADS) void scatter_kernel(
    const int* __restrict__ src, const int* __restrict__ dst,
    const int* __restrict__ bmat, const int* __restrict__ bcnt,
    u32* __restrict__ pairs, int e, int nbuck, int valn)
{
    __shared__ int base_s[BSIZE], cur[BSIZE], s2[S1THREADS];
    const int tid = threadIdx.x;
    const int c0  = blockIdx.x * PASS1_CHUNK;

    // local exclusive scan of bcnt -> bbase
    int v = (tid < nbuck) ? bcnt[tid] : 0;
    s2[tid] = v;
    __syncthreads();
    for (int off = 1; off < S1THREADS; off <<= 1) {
        int t = (tid >= off) ? s2[tid - off] : 0;
        __syncthreads();
        s2[tid] += t;
        __syncthreads();
    }
    if (tid < nbuck) {
        base_s[tid] = (s2[tid] - v) + bmat[blockIdx.x * nbuck + tid];
        cur[tid] = 0;
    }
    __syncthreads();

    if (valn) {
        for (int i = tid * 4; i < PASS1_CHUNK; i += S1THREADS * 4) {
            int idx = c0 + i;
            if (idx + 3 < e) {
                int4 dv = *(const int4*)(dst + idx);
                int4 sv = *(const int4*)(src + idx);
                int dd[4] = {dv.x, dv.y, dv.z, dv.w};
                int ss[4] = {sv.x, sv.y, sv.z, sv.w};
#pragma unroll
                for (int k = 0; k < 4; ++k) {
                    int b = dd[k] >> BSHIFT;
                    int off = atomicAdd(&cur[b], 1);
                    pairs[base_s[b] + off] =
                        ((u32)(dd[k] & (BSIZE - 1)) << SRC_BITS) | (u32)ss[k];
                }
            } else {
                for (int k = 0; k < 4; ++k) {
                    if (idx + k < e) {
                        int d = dst[idx + k];
                        int b = d >> BSHIFT;
                        int off = atomicAdd(&cur[b], 1);
                        pairs[base_s[b] + off] =
                            ((u32)(d & (BSIZE - 1)) << SRC_BITS) | (u32)src[idx + k];
                    }
                }
            }
        }
    } else {
        for (int i = tid; i < PASS1_CHUNK; i += S1THREADS) {
            int idx = c0 + i;
            if (idx < e) {
                int d = dst[idx];
                int b = d >> BSHIFT;
                int off = atomicAdd(&cur[b], 1);
                pairs[base_s[b] + off] = ((u32)(d & (BSIZE - 1)) << SRC_BITS) | (u32)src[idx];
            }
        }
    }
}

// ---------------- sort pass 2: degree count + rowptr + dis + csr scatter ------

__global__ __launch_bounds__(S1THREADS) void sort2_kernel(
    const int* __restrict__ bcnt, const u32* __restrict__ pairs,
    int* __restrict__ rowptr, float* __restrict__ dis,
    int* __restrict__ csr, int n, int e, int nbuck)
{
    __shared__ int cnt[BSIZE];
    __shared__ int cur[BSIZE];
    __shared__ int s2[S1THREADS];
    __shared__ u32 pst[S2CAP];
    __shared__ int p0s, p1s;

    const int b  = blockIdx.x;
    const int d0 = b << BSHIFT;
    const int nd = min(BSIZE, n - d0);
    const int tid = threadIdx.x;

    // local scan of bcnt: p0 = exclusive[b], p1 = inclusive[b]
    int v = (tid < nbuck) ? bcnt[tid] : 0;
    s2[tid] = v;
    __syncthreads();
    for (int off = 1; off < S1THREADS; off <<= 1) {
        int t = (tid >= off) ? s2[tid - off] : 0;
        __syncthreads();
        s2[tid] += t;
        __syncthreads();
    }
    if (tid == b) { p0s = s2[tid] - v; p1s = s2[tid]; }
    __syncthreads();
    const int p0 = p0s, p1 = p1s;
    const int sz = p1 - p0;

    for (int i = tid; i < BSIZE; i += S1THREADS) cnt[i] = 0;
    __syncthreads();

    for (int j = tid; j < sz; j += S1THREADS) {
        u32 pr = pairs[p0 + j];
        if (j < S2CAP) pst[j] = pr;
        atomicAdd(&cnt[pr >> SRC_BITS], 1);
    }
    __syncthreads();

    int cv = cnt[tid];
    s2[tid] = cv;
    __syncthreads();
    for (int off = 1; off < S1THREADS; off <<= 1) {
        int t = (tid >= off) ? s2[tid - off] : 0;
        __syncthreads();
        s2[tid] += t;
        __syncthreads();
    }
    cur[tid] = p0 + s2[tid] - cv;
    __syncthreads();

    for (int i = tid; i < nd; i += S1THREADS) {
        rowptr[d0 + i] = cur[i];
        dis[d0 + i] = rsqrtf((float)(cnt[i] + 1));   // +1 self-loop
    }
    if (b == nbuck - 1 && tid == 0) rowptr[n] = e;
    __syncthreads();

    for (int j = tid; j < sz; j += S1THREADS) {
        u32 pr = (j < S2CAP) ? pst[j] : pairs[p0 + j];
        int pos = atomicAdd(&cur[pr >> SRC_BITS], 1);
        csr[pos] = (int)(pr & ((1u << SRC_BITS) - 1));
    }
}

// ---------------- MFMA GEMM (layer 1: fp32 input, no pre-activation) ----------
// hs[r] = bf16( (bf16(Xf[r]) @ W) * dis[r] )
template <int KTOT, int OUT, int SOUT>
__global__ __launch_bounds__(THREADS) void mfma_gemm_kernel(
    const float* __restrict__ Xf, const float* __restrict__ W,
    const float* __restrict__ dis, u16* __restrict__ hs, int n)
{
    constexpr int NCG = (OUT + 15) / 16;
    constexpr int CC  = NCG * 16;
    constexpr int NKK = KTOT / 32;
    constexpr int WS  = KTOT + 8;

    __shared__ u16 WT[CC][WS];                // B^T bf16

    const int tid = threadIdx.x;
    for (int idx = tid; idx < KTOT * CC; idx += THREADS) {
        int k = idx / CC;
        int c = idx - k * CC;
        float v = (c < OUT) ? W[k * OUT + c] : 0.f;
        WT[c][k] = f2bf(v);
    }
    __syncthreads();

    const int lane  = tid & 63;
    const int rlane = lane & 15;
    const int kgrp  = lane >> 4;
    const int rbase = blockIdx.x * 64 + (tid >> 6) * 16;
    const int arow = min(rbase + rlane, n - 1);

    float4v acc[NCG];
#pragma unroll
    for (int g = 0; g < NCG; ++g) acc[g] = (float4v)(0.f);

#pragma unroll
    for (int kk = 0; kk < NKK; ++kk) {
        const int kb = kk * 32 + kgrp * 8;
        short8v a;
        float4 f0 = *(const float4*)(Xf + (size_t)arow * KTOT + kb);
        float4 f1 = *(const float4*)(Xf + (size_t)arow * KTOT + kb + 4);
        a[0] = (short)f2bf(f0.x); a[1] = (short)f2bf(f0.y);
        a[2] = (short)f2bf(f0.z); a[3] = (short)f2bf(f0.w);
        a[4] = (short)f2bf(f1.x); a[5] = (short)f2bf(f1.y);
        a[6] = (short)f2bf(f1.z); a[7] = (short)f2bf(f1.w);
#pragma unroll
        for (int g = 0; g < NCG; ++g) {
            short8v b = *(const short8v*)&WT[g * 16 + rlane][kb];
            acc[g] = __builtin_amdgcn_mfma_f32_16x16x32_bf16(a, b, acc[g], 0, 0, 0);
        }
    }

#pragma unroll
    for (int j = 0; j < 4; ++j) {
        int row = rbase + kgrp * 4 + j;
        if (row < n) {
            float dd = dis[row];
#pragma unroll
            for (int g = 0; g < NCG; ++g) {
                int col = g * 16 + rlane;
                if (OUT == CC || col < OUT)
                    hs[(size_t)row * SOUT + col] = f2bf(acc[g][j] * dd);
            }
        }
    }
}

// ---------------- fused gather-aggregate + swish + MFMA GEMM ------------------
// Phase 1 gathers 16-deep: two csr words (16 edges) per batch, all 16 uint4
// gathers issued before accumulation (256B in flight per lane).
template <int OUT, int SOUT>
__global__ __launch_bounds__(THREADS) void fused_agg_gemm_kernel(
    const int* __restrict__ rowptr, const int* __restrict__ csr,
    const u16* __restrict__ hs, const float* __restrict__ W,
    const float* __restrict__ bin, const float* __restrict__ dis,
    u16* __restrict__ hsout, int n)
{
    constexpr int KTOT = 64;
    constexpr int NCG = (OUT + 15) / 16;
    constexpr int CC  = NCG * 16;
    constexpr int WS  = KTOT + 8;

    __shared__ u16 WT[CC][WS];                // B^T bf16
    __shared__ u16 As[64][WS];                // aggregated+activated A tile

    const int tid = threadIdx.x;
    for (int idx = tid; idx < KTOT * CC; idx += THREADS) {
        int k = idx / CC;
        int c = idx - k * CC;
        float v = (c < OUT) ? W[k * OUT + c] : 0.f;
        WT[c][k] = f2bf(v);
    }

    const int lane = tid & 63;
    const int wid  = tid >> 6;
    const int sub  = lane >> 3;               // subgroup 0..7 (one row each)
    const int gl   = lane & 7;
    const int c8   = gl * 8;
    const int row0 = blockIdx.x * 64;

    // ---- phase 1: gather-aggregate 64 rows (2 halves x 32 rows) ----
#pragma unroll
    for (int half = 0; half < 2; ++half) {
        const int lr = half * 32 + wid * 8 + sub;   // local row 0..63
        const int d  = row0 + lr;
        if (d < n) {
            const int beg = rowptr[d], end = rowptr[d + 1];
            float acc[8];
            {
                uint4 u = *(const uint4*)(hs + (size_t)d * 64 + c8);  // self-loop
                acc[0] = bf_lo(u.x); acc[1] = bf_hi(u.x);
                acc[2] = bf_lo(u.y); acc[3] = bf_hi(u.y);
                acc[4] = bf_lo(u.z); acc[5] = bf_hi(u.z);
                acc[6] = bf_lo(u.w); acc[7] = bf_hi(u.w);
            }
            int e0 = (beg + gl < end) ? csr[beg + gl] : 0;
            int e1 = (beg + 8 + gl < end) ? csr[beg + 8 + gl] : 0;
            for (int t = beg; t < end; t += 16) {
                const int m = end - t;
                uint4 ub[16];
#pragma unroll
                for (int q = 0; q < 16; ++q) {          // issue 16 gathers
                    int s = __shfl((q < 8) ? e0 : e1, (sub << 3) + (q & 7));
                    if (q < m) ub[q] = *(const uint4*)(hs + (size_t)s * 64 + c8);
                }
                e0 = (t + 16 + gl < end) ? csr[t + 16 + gl] : 0;   // prefetch
                e1 = (t + 24 + gl < end) ? csr[t + 24 + gl] : 0;
#pragma unroll
                for (int q = 0; q < 16; ++q) {
                    if (q < m) {
                        acc[0] += bf_lo(ub[q].x); acc[1] += bf_hi(ub[q].x);
                        acc[2] += bf_lo(ub[q].y); acc[3] += bf_hi(ub[q].y);
                        acc[4] += bf_lo(ub[q].z); acc[5] += bf_hi(ub[q].z);
                        acc[6] += bf_lo(ub[q].w); acc[7] += bf_hi(ub[q].w);
                    }
                }
            }
            // swish(agg*dis + b) -> bf16 A row
            float dd = dis[d];
            u16 o[8];
#pragma unroll
            for (int q = 0; q < 8; ++q) {
                float h = acc[q] * dd + bin[c8 + q];
                o[q] = f2bf(h / (1.f + __expf(-h)));
            }
            ushort4 o0 = {o[0], o[1], o[2], o[3]};
            ushort4 o1 = {o[4], o[5], o[6], o[7]};
            *(ushort4*)&As[lr][c8]     = o0;
            *(ushort4*)&As[lr][c8 + 4] = o1;
        }
    }
    __syncthreads();

    // ---- phase 2: MFMA from LDS ----
    const int rlane = lane & 15;
    const int kgrp  = lane >> 4;
    const int rbase = row0 + wid * 16;

    float4v acc[NCG];
#pragma unroll
    for (int g = 0; g < NCG; ++g) acc[g] = (float4v)(0.f);

#pragma unroll
    for (int kk = 0; kk < 2; ++kk) {
        const int kb = kk * 32 + kgrp * 8;
        short8v a = *(const short8v*)&As[wid * 16 + rlane][kb];
#pragma unroll
        for (int g = 0; g < NCG; ++g) {
            short8v b = *(const short8v*)&WT[g * 16 + rlane][kb];
            acc[g] = __builtin_amdgcn_mfma_f32_16x16x32_bf16(a, b, acc[g], 0, 0, 0);
        }
    }

#pragma unroll
    for (int j = 0; j < 4; ++j) {
        int row = rbase + kgrp * 4 + j;
        if (row < n) {
            float dd = dis[row];
#pragma unroll
            for (int g = 0; g < NCG; ++g) {
                int col = g * 16 + rlane;
                if (OUT == CC || col < OUT)
                    hsout[(size_t)row * SOUT + col] = f2bf(acc[g][j] * dd);
            }
        }
    }
}

// ---------------- layer-3 aggregate + bias + log_softmax ----------------------
// hs3 rows: 40 bf16 at stride 40 (80B). One 8-lane subgroup per row; 16-deep
// gather pipeline as in the fused kernel.
__global__ __launch_bounds__(THREADS) void agg40_lsm_kernel(
    const int* __restrict__ rowptr, const int* __restrict__ csr,
    const u16* __restrict__ hs, const float* __restrict__ dis,
    const float* __restrict__ b3, float* __restrict__ out, int n)
{
    constexpr int S = 40;
    const int lane = threadIdx.x & 63;
    const int sub  = lane >> 3;
    const int gl   = lane & 7;
    const int d = (blockIdx.x * 4 + (threadIdx.x >> 6)) * 8 + sub;
    if (d >= n) return;
    const bool act = (gl < 5);
    const int c8 = gl * 8;

    const int beg = rowptr[d], end = rowptr[d + 1];
    float acc[8] = {0.f,0.f,0.f,0.f,0.f,0.f,0.f,0.f};
    if (act) {
        uint4 u = *(const uint4*)(hs + (size_t)d * S + c8);
        acc[0] = bf_lo(u.x); acc[1] = bf_hi(u.x);
        acc[2] = bf_lo(u.y); acc[3] = bf_hi(u.y);
        acc[4] = bf_lo(u.z); acc[5] = bf_hi(u.z);
        acc[6] = bf_lo(u.w); acc[7] = bf_hi(u.w);
    }

    int e0 = (beg + gl < end) ? csr[beg + gl] : 0;
    int e1 = (beg + 8 + gl < end) ? csr[beg + 8 + gl] : 0;
    for (int t = beg; t < end; t += 16) {
        const int m = end - t;
        uint4 ub[16];
#pragma unroll
        for (int q = 0; q < 16; ++q) {
            int s = __shfl((q < 8) ? e0 : e1, (sub << 3) + (q & 7));
            if (q < m && act) ub[q] = *(const uint4*)(hs + (size_t)s * S + c8);
        }
        e0 = (t + 16 + gl < end) ? csr[t + 16 + gl] : 0;
        e1 = (t + 24 + gl < end) ? csr[t + 24 + gl] : 0;
#pragma unroll
        for (int q = 0; q < 16; ++q) {
            if (q < m && act) {
                acc[0] += bf_lo(ub[q].x); acc[1] += bf_hi(ub[q].x);
                acc[2] += bf_lo(ub[q].y); acc[3] += bf_hi(ub[q].y);
                acc[4] += bf_lo(ub[q].z); acc[5] += bf_hi(ub[q].z);
                acc[6] += bf_lo(ub[q].w); acc[7] += bf_hi(ub[q].w);
            }
        }
    }

    float val[8];
    float mx = -1e30f;
    if (act) {
        float dd = dis[d];
#pragma unroll
        for (int q = 0; q < 8; ++q) {
            val[q] = acc[q] * dd + b3[c8 + q];
            mx = fmaxf(mx, val[q]);
        }
    }
#pragma unroll
    for (int off = 4; off > 0; off >>= 1) mx = fmaxf(mx, __shfl_xor(mx, off));
    float es = 0.f;
    if (act) {
#pragma unroll
        for (int q = 0; q < 8; ++q) es += __expf(val[q] - mx);
    }
#pragma unroll
    for (int off = 4; off > 0; off >>= 1) es += __shfl_xor(es, off);
    float lse = mx + __logf(es);
    if (act) {
        float4 o0 = make_float4(val[0]-lse, val[1]-lse, val[2]-lse, val[3]-lse);
        float4 o1 = make_float4(val[4]-lse, val[5]-lse, val[6]-lse, val[7]-lse);
        *(float4*)(out + (size_t)d * 40 + c8)     = o0;
        *(float4*)(out + (size_t)d * 40 + c8 + 4) = o1;
    }
}

// ---------------- launch ----------------
static inline size_t align_up(size_t v, size_t a) { return (v + a - 1) & ~(a - 1); }

extern "C" void kernel_launch(void* const* d_in, const int* in_sizes, int n_in,
                              void* d_out, int out_size, void* d_ws, size_t ws_size,
                              hipStream_t stream) {
    const float* x  = (const float*)d_in[0];
    const int*   ei = (const int*)d_in[1];
    const float* W1 = (const float*)d_in[2];
    const float* b1 = (const float*)d_in[3];
    const float* W2 = (const float*)d_in[4];
    const float* b2 = (const float*)d_in[5];
    const float* W3 = (const float*)d_in[6];
    const float* b3 = (const float*)d_in[7];
    float* out = (float*)d_out;

    const int n = in_sizes[0] / 128;
    const int e = in_sizes[1] / 2;
    const int* src = ei;
    const int* dst = ei + e;
    const int valn = (((uintptr_t)src & 15) == 0 && ((uintptr_t)dst & 15) == 0) ? 1 : 0;

    const int nbuck = (n + BSIZE - 1) >> BSHIFT;            // 196 for n=100k
    const int nblk  = (e + PASS1_CHUNK - 1) / PASS1_CHUNK;  // 391

    // workspace: dis[n] | rowptr[n+1] | bcnt[1k] |
    //            hmat[nblk*nbuck] | bmat[nblk*nbuck] | csr[e] |
    //            hsb (n*64 u16) | hs2b (n*64 u16)
    // pairs u32[e] aliases hsb (consumed in sort2 before gemm1 writes hsb).
    char* base = (char*)d_ws;
    size_t off = 0;
    float* dis = (float*)(base + off);    off = align_up(off + (size_t)n * 4, 256);
    int* rowptr = (int*)(base + off);     off = align_up(off + (size_t)(n + 1) * 4, 256);
    int* bcnt = (int*)(base + off);       off = align_up(off + 1024 * 4, 256);
    int* hmat = (int*)(base + off);       off = align_up(off + (size_t)nblk * nbuck * 4, 256);
    int* bmat = (int*)(base + off);       off = align_up(off + (size_t)nblk * nbuck * 4, 256);
    int* csr = (int*)(base + off);        off = align_up(off + (size_t)e * 4, 256);
    u16* hsb = (u16*)(base + off);        off = align_up(off + (size_t)n * 64 * 2, 256);
    u16* hs2b = (u16*)(base + off);       off = align_up(off + (size_t)n * 64 * 2, 256);
    u32* pairs = (u32*)hsb;

    const int gb_rows = (n + 63) / 64;
    const int gb_agg  = (n + 31) / 32;

    // CSR build (deterministic, no global atomics; 4 kernels)
    hist_kernel<<<nblk, S1THREADS, 0, stream>>>(dst, hmat, e, nbuck, valn);
    colscan_kernel<<<nbuck, THREADS, 0, stream>>>(hmat, bmat, bcnt, nblk, nbuck);
    scatter_kernel<<<nblk, S1THREADS, 0, stream>>>(src, dst, bmat, bcnt, pairs, e, nbuck, valn);
    sort2_kernel<<<nbuck, S1THREADS, 0, stream>>>(bcnt, pairs, rowptr, dis, csr, n, e, nbuck);

    // layer 1: x @ W1 -> hsb (hs1, bf16)
    mfma_gemm_kernel<128, 64, 64><<<gb_rows, THREADS, 0, stream>>>(x, W1, dis, hsb, n);

    // layer 2 fused: gather-agg(hs1) + swish(+b1) + @W2 -> hs2b (hs2)
    fused_agg_gemm_kernel<64, 64><<<gb_rows, THREADS, 0, stream>>>(
        rowptr, csr, hsb, W2, b1, dis, hs2b, n);

    // layer 3 fused: gather-agg(hs2) + swish(+b2) + @W3 -> hsb (hs3, stride 40)
    fused_agg_gemm_kernel<40, 40><<<gb_rows, THREADS, 0, stream>>>(
        rowptr, csr, hs2b, W3, b2, dis, hsb, n);

    // final: gather-agg(hs3) + bias + log_softmax -> out
    agg40_lsm_kernel<<<gb_agg, THREADS, 0, stream>>>(rowptr, csr, hsb, dis, b3, out, n);
}

// Round 15
// 171.235 us; speedup vs baseline: 1.0613x; 1.0613x over previous
//
#include <hip/hip_runtime.h>
#include <math.h>

#define THREADS 256
#define S1THREADS 512
#define BSHIFT 9              // 512 dsts per bucket
#define BSIZE (1 << BSHIFT)
#define PASS1_CHUNK 4096
#define SRC_BITS 17           // n < 131072
#define S2CAP 12288           // sort2 LDS pair-stage capacity (48KB)

typedef unsigned int u32;
typedef unsigned short u16;
typedef __attribute__((ext_vector_type(8))) short short8v;   // 8 bf16 (4 VGPR)
typedef __attribute__((ext_vector_type(4))) float float4v;   // MFMA acc

__device__ __forceinline__ u16 f2bf(float f) {      // RNE fp32 -> bf16
    u32 u = __float_as_uint(f);
    u = (u + 0x7fffu + ((u >> 16) & 1u)) >> 16;
    return (u16)u;
}
__device__ __forceinline__ float bf_lo(u32 u) { return __uint_as_float(u << 16); }
__device__ __forceinline__ float bf_hi(u32 u) { return __uint_as_float(u & 0xffff0000u); }

// ---------------- phase 1: per-block bucket histogram -> hmat[blk][bucket] ----

__global__ __launch_bounds__(S1THREADS) void hist_kernel(
    const int* __restrict__ dst, int* __restrict__ hmat, int e, int nbuck, int valn)
{
    __shared__ int hist[BSIZE];
    const int tid = threadIdx.x;
    const int c0  = blockIdx.x * PASS1_CHUNK;
    for (int i = tid; i < nbuck; i += S1THREADS) hist[i] = 0;
    __syncthreads();
    if (valn) {   // 16B-aligned dst, 4 edges per iter
        for (int i = tid * 4; i < PASS1_CHUNK; i += S1THREADS * 4) {
            int idx = c0 + i;
            if (idx + 3 < e) {
                int4 dv = *(const int4*)(dst + idx);
                atomicAdd(&hist[dv.x >> BSHIFT], 1);
                atomicAdd(&hist[dv.y >> BSHIFT], 1);
                atomicAdd(&hist[dv.z >> BSHIFT], 1);
                atomicAdd(&hist[dv.w >> BSHIFT], 1);
            } else {
                for (int k = 0; k < 4; ++k)
                    if (idx + k < e) atomicAdd(&hist[dst[idx + k] >> BSHIFT], 1);
            }
        }
    } else {
        for (int i = tid; i < PASS1_CHUNK; i += S1THREADS) {
            int idx = c0 + i;
            if (idx < e) atomicAdd(&hist[dst[idx] >> BSHIFT], 1);
        }
    }
    __syncthreads();
    for (int b = tid; b < nbuck; b += S1THREADS)
        hmat[blockIdx.x * nbuck + b] = hist[b];
}

// ---------------- phase 2: column scan of hmat -> bmat (relative), bcnt -------

__global__ __launch_bounds__(THREADS) void colscan_kernel(
    const int* __restrict__ hmat, int* __restrict__ bmat,
    int* __restrict__ bcnt, int nblk, int nbuck)
{
    __shared__ int s[THREADS];
    const int b = blockIdx.x, tid = threadIdx.x;
    int run = 0;
    for (int t0 = 0; t0 < nblk; t0 += THREADS) {
        int idx = t0 + tid;
        int v = (idx < nblk) ? hmat[idx * nbuck + b] : 0;
        s[tid] = v;
        __syncthreads();
        for (int off = 1; off < THREADS; off <<= 1) {
            int t = (tid >= off) ? s[tid - off] : 0;
            __syncthreads();
            s[tid] += t;
            __syncthreads();
        }
        if (idx < nblk) bmat[idx * nbuck + b] = run + s[tid] - v;
        run += s[THREADS - 1];
        __syncthreads();
    }
    if (tid == 0) bcnt[b] = run;
}

// ---------------- phase 3: scatter packed (ld<<17|src) into bucket regions ----

__global__ __launch_bounds__(S1THREADS) void scatter_kernel(
    const int* __restrict__ src, const int* __restrict__ dst,
    const int* __restrict__ bmat, const int* __restrict__ bcnt,
    u32* __restrict__ pairs, int e, int nbuck, int valn)
{
    __shared__ int base_s[BSIZE], cur[BSIZE], s2[S1THREADS];
    const int tid = threadIdx.x;
    const int c0  = blockIdx.x * PASS1_CHUNK;

    // local exclusive scan of bcnt -> bbase
    int v = (tid < nbuck) ? bcnt[tid] : 0;
    s2[tid] = v;
    __syncthreads();
    for (int off = 1; off < S1THREADS; off <<= 1) {
        int t = (tid >= off) ? s2[tid - off] : 0;
        __syncthreads();
        s2[tid] += t;
        __syncthreads();
    }
    if (tid < nbuck) {
        base_s[tid] = (s2[tid] - v) + bmat[blockIdx.x * nbuck + tid];
        cur[tid] = 0;
    }
    __syncthreads();

    if (valn) {
        for (int i = tid * 4; i < PASS1_CHUNK; i += S1THREADS * 4) {
            int idx = c0 + i;
            if (idx + 3 < e) {
                int4 dv = *(const int4*)(dst + idx);
                int4 sv = *(const int4*)(src + idx);
                int dd[4] = {dv.x, dv.y, dv.z, dv.w};
                int ss[4] = {sv.x, sv.y, sv.z, sv.w};
#pragma unroll
                for (int k = 0; k < 4; ++k) {
                    int b = dd[k] >> BSHIFT;
                    int off = atomicAdd(&cur[b], 1);
                    pairs[base_s[b] + off] =
                        ((u32)(dd[k] & (BSIZE - 1)) << SRC_BITS) | (u32)ss[k];
                }
            } else {
                for (int k = 0; k < 4; ++k) {
                    if (idx + k < e) {
                        int d = dst[idx + k];
                        int b = d >> BSHIFT;
                        int off = atomicAdd(&cur[b], 1);
                        pairs[base_s[b] + off] =
                            ((u32)(d & (BSIZE - 1)) << SRC_BITS) | (u32)src[idx + k];
                    }
                }
            }
        }
    } else {
        for (int i = tid; i < PASS1_CHUNK; i += S1THREADS) {
            int idx = c0 + i;
            if (idx < e) {
                int d = dst[idx];
                int b = d >> BSHIFT;
                int off = atomicAdd(&cur[b], 1);
                pairs[base_s[b] + off] = ((u32)(d & (BSIZE - 1)) << SRC_BITS) | (u32)src[idx];
            }
        }
    }
}

// ---------------- sort pass 2: degree count + rowptr + dis + csr scatter ------

__global__ __launch_bounds__(S1THREADS) void sort2_kernel(
    const int* __restrict__ bcnt, const u32* __restrict__ pairs,
    int* __restrict__ rowptr, float* __restrict__ dis,
    int* __restrict__ csr, int n, int e, int nbuck)
{
    __shared__ int cnt[BSIZE];
    __shared__ int cur[BSIZE];
    __shared__ int s2[S1THREADS];
    __shared__ u32 pst[S2CAP];
    __shared__ int p0s, p1s;

    const int b  = blockIdx.x;
    const int d0 = b << BSHIFT;
    const int nd = min(BSIZE, n - d0);
    const int tid = threadIdx.x;

    // local scan of bcnt: p0 = exclusive[b], p1 = inclusive[b]
    int v = (tid < nbuck) ? bcnt[tid] : 0;
    s2[tid] = v;
    __syncthreads();
    for (int off = 1; off < S1THREADS; off <<= 1) {
        int t = (tid >= off) ? s2[tid - off] : 0;
        __syncthreads();
        s2[tid] += t;
        __syncthreads();
    }
    if (tid == b) { p0s = s2[tid] - v; p1s = s2[tid]; }
    __syncthreads();
    const int p0 = p0s, p1 = p1s;
    const int sz = p1 - p0;

    for (int i = tid; i < BSIZE; i += S1THREADS) cnt[i] = 0;
    __syncthreads();

    for (int j = tid; j < sz; j += S1THREADS) {
        u32 pr = pairs[p0 + j];
        if (j < S2CAP) pst[j] = pr;
        atomicAdd(&cnt[pr >> SRC_BITS], 1);
    }
    __syncthreads();

    int cv = cnt[tid];
    s2[tid] = cv;
    __syncthreads();
    for (int off = 1; off < S1THREADS; off <<= 1) {
        int t = (tid >= off) ? s2[tid - off] : 0;
        __syncthreads();
        s2[tid] += t;
        __syncthreads();
    }
    cur[tid] = p0 + s2[tid] - cv;
    __syncthreads();

    for (int i = tid; i < nd; i += S1THREADS) {
        rowptr[d0 + i] = cur[i];
        dis[d0 + i] = rsqrtf((float)(cnt[i] + 1));   // +1 self-loop
    }
    if (b == nbuck - 1 && tid == 0) rowptr[n] = e;
    __syncthreads();

    for (int j = tid; j < sz; j += S1THREADS) {
        u32 pr = (j < S2CAP) ? pst[j] : pairs[p0 + j];
        int pos = atomicAdd(&cur[pr >> SRC_BITS], 1);
        csr[pos] = (int)(pr & ((1u << SRC_BITS) - 1));
    }
}

// ---------------- MFMA GEMM (layer 1: fp32 input, no pre-activation) ----------
// hs[r] = bf16( (bf16(Xf[r]) @ W) * dis[r] )
template <int KTOT, int OUT, int SOUT>
__global__ __launch_bounds__(THREADS) void mfma_gemm_kernel(
    const float* __restrict__ Xf, const float* __restrict__ W,
    const float* __restrict__ dis, u16* __restrict__ hs, int n)
{
    constexpr int NCG = (OUT + 15) / 16;
    constexpr int CC  = NCG * 16;
    constexpr int NKK = KTOT / 32;
    constexpr int WS  = KTOT + 8;

    __shared__ u16 WT[CC][WS];                // B^T bf16

    const int tid = threadIdx.x;
    for (int idx = tid; idx < KTOT * CC; idx += THREADS) {
        int k = idx / CC;
        int c = idx - k * CC;
        float v = (c < OUT) ? W[k * OUT + c] : 0.f;
        WT[c][k] = f2bf(v);
    }
    __syncthreads();

    const int lane  = tid & 63;
    const int rlane = lane & 15;
    const int kgrp  = lane >> 4;
    const int rbase = blockIdx.x * 64 + (tid >> 6) * 16;
    const int arow = min(rbase + rlane, n - 1);

    float4v acc[NCG];
#pragma unroll
    for (int g = 0; g < NCG; ++g) acc[g] = (float4v)(0.f);

#pragma unroll
    for (int kk = 0; kk < NKK; ++kk) {
        const int kb = kk * 32 + kgrp * 8;
        short8v a;
        float4 f0 = *(const float4*)(Xf + (size_t)arow * KTOT + kb);
        float4 f1 = *(const float4*)(Xf + (size_t)arow * KTOT + kb + 4);
        a[0] = (short)f2bf(f0.x); a[1] = (short)f2bf(f0.y);
        a[2] = (short)f2bf(f0.z); a[3] = (short)f2bf(f0.w);
        a[4] = (short)f2bf(f1.x); a[5] = (short)f2bf(f1.y);
        a[6] = (short)f2bf(f1.z); a[7] = (short)f2bf(f1.w);
#pragma unroll
        for (int g = 0; g < NCG; ++g) {
            short8v b = *(const short8v*)&WT[g * 16 + rlane][kb];
            acc[g] = __builtin_amdgcn_mfma_f32_16x16x32_bf16(a, b, acc[g], 0, 0, 0);
        }
    }

#pragma unroll
    for (int j = 0; j < 4; ++j) {
        int row = rbase + kgrp * 4 + j;
        if (row < n) {
            float dd = dis[row];
#pragma unroll
            for (int g = 0; g < NCG; ++g) {
                int col = g * 16 + rlane;
                if (OUT == CC || col < OUT)
                    hs[(size_t)row * SOUT + col] = f2bf(acc[g][j] * dd);
            }
        }
    }
}

// ---------------- fused gather-aggregate + swish + MFMA GEMM ------------------
// Phase 1: each wave aggregates the 16 rows its own MFMA consumes
// (lr = wid*16 + half*8 + sub) -> As dependency is wave-local, so no barrier
// between gather and MFMA (within-wave LDS ordering via lgkmcnt).
template <int OUT, int SOUT>
__global__ __launch_bounds__(THREADS) void fused_agg_gemm_kernel(
    const int* __restrict__ rowptr, const int* __restrict__ csr,
    const u16* __restrict__ hs, const float* __restrict__ W,
    const float* __restrict__ bin, const float* __restrict__ dis,
    u16* __restrict__ hsout, int n)
{
    constexpr int KTOT = 64;
    constexpr int NCG = (OUT + 15) / 16;
    constexpr int CC  = NCG * 16;
    constexpr int WS  = KTOT + 8;

    __shared__ u16 WT[CC][WS];                // B^T bf16
    __shared__ u16 As[64][WS];                // aggregated+activated A tile

    const int tid = threadIdx.x;
    for (int idx = tid; idx < KTOT * CC; idx += THREADS) {
        int k = idx / CC;
        int c = idx - k * CC;
        float v = (c < OUT) ? W[k * OUT + c] : 0.f;
        WT[c][k] = f2bf(v);
    }
    __syncthreads();                          // WT visible to all (only barrier)

    const int lane = tid & 63;
    const int wid  = tid >> 6;
    const int sub  = lane >> 3;               // subgroup 0..7 (one row each)
    const int gl   = lane & 7;
    const int c8   = gl * 8;
    const int row0 = blockIdx.x * 64;

    // ---- phase 1: gather-aggregate this wave's 16 rows (2 halves x 8) ----
#pragma unroll
    for (int half = 0; half < 2; ++half) {
        const int lr = wid * 16 + half * 8 + sub;   // wave-owned local row
        const int d  = row0 + lr;
        if (d < n) {
            const int beg = rowptr[d], end = rowptr[d + 1];
            float acc[8];
            {
                uint4 u = *(const uint4*)(hs + (size_t)d * 64 + c8);  // self-loop
                acc[0] = bf_lo(u.x); acc[1] = bf_hi(u.x);
                acc[2] = bf_lo(u.y); acc[3] = bf_hi(u.y);
                acc[4] = bf_lo(u.z); acc[5] = bf_hi(u.z);
                acc[6] = bf_lo(u.w); acc[7] = bf_hi(u.w);
            }
            int eidx = (beg + gl < end) ? csr[beg + gl] : 0;
            for (int t = beg; t < end; t += 8) {
                const int m = end - t;
                uint4 ub[8];
#pragma unroll
                for (int q = 0; q < 8; ++q) {           // issue 8 gathers
                    int s = __shfl(eidx, (sub << 3) + q);
                    if (q < m) ub[q] = *(const uint4*)(hs + (size_t)s * 64 + c8);
                }
                int eidx_n = (t + 8 + gl < end) ? csr[t + 8 + gl] : 0;  // prefetch
#pragma unroll
                for (int q = 0; q < 8; ++q) {
                    if (q < m) {
                        acc[0] += bf_lo(ub[q].x); acc[1] += bf_hi(ub[q].x);
                        acc[2] += bf_lo(ub[q].y); acc[3] += bf_hi(ub[q].y);
                        acc[4] += bf_lo(ub[q].z); acc[5] += bf_hi(ub[q].z);
                        acc[6] += bf_lo(ub[q].w); acc[7] += bf_hi(ub[q].w);
                    }
                }
                eidx = eidx_n;
            }
            // swish(agg*dis + b) -> bf16 A row
            float dd = dis[d];
            u16 o[8];
#pragma unroll
            for (int q = 0; q < 8; ++q) {
                float h = acc[q] * dd + bin[c8 + q];
                o[q] = f2bf(h / (1.f + __expf(-h)));
            }
            ushort4 o0 = {o[0], o[1], o[2], o[3]};
            ushort4 o1 = {o[4], o[5], o[6], o[7]};
            *(ushort4*)&As[lr][c8]     = o0;
            *(ushort4*)&As[lr][c8 + 4] = o1;
        }
    }
    // no barrier: MFMA below reads only As rows this wave wrote

    // ---- phase 2: MFMA from LDS ----
    const int rlane = lane & 15;
    const int kgrp  = lane >> 4;
    const int rbase = row0 + wid * 16;

    float4v acc[NCG];
#pragma unroll
    for (int g = 0; g < NCG; ++g) acc[g] = (float4v)(0.f);

#pragma unroll
    for (int kk = 0; kk < 2; ++kk) {
        const int kb = kk * 32 + kgrp * 8;
        short8v a = *(const short8v*)&As[wid * 16 + rlane][kb];
#pragma unroll
        for (int g = 0; g < NCG; ++g) {
            short8v b = *(const short8v*)&WT[g * 16 + rlane][kb];
            acc[g] = __builtin_amdgcn_mfma_f32_16x16x32_bf16(a, b, acc[g], 0, 0, 0);
        }
    }

#pragma unroll
    for (int j = 0; j < 4; ++j) {
        int row = rbase + kgrp * 4 + j;
        if (row < n) {
            float dd = dis[row];
#pragma unroll
            for (int g = 0; g < NCG; ++g) {
                int col = g * 16 + rlane;
                if (OUT == CC || col < OUT)
                    hsout[(size_t)row * SOUT + col] = f2bf(acc[g][j] * dd);
            }
        }
    }
}

// ---------------- layer-3 aggregate + bias + log_softmax ----------------------
// hs3 rows: 40 bf16 at stride 40 (80B). One 8-lane subgroup per row; 8-deep
// pipelined gather batch.
__global__ __launch_bounds__(THREADS) void agg40_lsm_kernel(
    const int* __restrict__ rowptr, const int* __restrict__ csr,
    const u16* __restrict__ hs, const float* __restrict__ dis,
    const float* __restrict__ b3, float* __restrict__ out, int n)
{
    constexpr int S = 40;
    const int lane = threadIdx.x & 63;
    const int sub  = lane >> 3;
    const int gl   = lane & 7;
    const int d = (blockIdx.x * 4 + (threadIdx.x >> 6)) * 8 + sub;
    if (d >= n) return;
    const bool act = (gl < 5);
    const int c8 = gl * 8;

    const int beg = rowptr[d], end = rowptr[d + 1];
    float acc[8] = {0.f,0.f,0.f,0.f,0.f,0.f,0.f,0.f};
    if (act) {
        uint4 u = *(const uint4*)(hs + (size_t)d * S + c8);
        acc[0] = bf_lo(u.x); acc[1] = bf_hi(u.x);
        acc[2] = bf_lo(u.y); acc[3] = bf_hi(u.y);
        acc[4] = bf_lo(u.z); acc[5] = bf_hi(u.z);
        acc[6] = bf_lo(u.w); acc[7] = bf_hi(u.w);
    }

    int eidx = (beg + gl < end) ? csr[beg + gl] : 0;
    for (int t = beg; t < end; t += 8) {
        const int m = end - t;
        uint4 ub[8];
#pragma unroll
        for (int q = 0; q < 8; ++q) {
            int s = __shfl(eidx, (sub << 3) + q);
            if (q < m && act) ub[q] = *(const uint4*)(hs + (size_t)s * S + c8);
        }
        int eidx_n = (t + 8 + gl < end) ? csr[t + 8 + gl] : 0;
#pragma unroll
        for (int q = 0; q < 8; ++q) {
            if (q < m && act) {
                acc[0] += bf_lo(ub[q].x); acc[1] += bf_hi(ub[q].x);
                acc[2] += bf_lo(ub[q].y); acc[3] += bf_hi(ub[q].y);
                acc[4] += bf_lo(ub[q].z); acc[5] += bf_hi(ub[q].z);
                acc[6] += bf_lo(ub[q].w); acc[7] += bf_hi(ub[q].w);
            }
        }
        eidx = eidx_n;
    }

    float val[8];
    float mx = -1e30f;
    if (act) {
        float dd = dis[d];
#pragma unroll
        for (int q = 0; q < 8; ++q) {
            val[q] = acc[q] * dd + b3[c8 + q];
            mx = fmaxf(mx, val[q]);
        }
    }
#pragma unroll
    for (int off = 4; off > 0; off >>= 1) mx = fmaxf(mx, __shfl_xor(mx, off));
    float es = 0.f;
    if (act) {
#pragma unroll
        for (int q = 0; q < 8; ++q) es += __expf(val[q] - mx);
    }
#pragma unroll
    for (int off = 4; off > 0; off >>= 1) es += __shfl_xor(es, off);
    float lse = mx + __logf(es);
    if (act) {
        float4 o0 = make_float4(val[0]-lse, val[1]-lse, val[2]-lse, val[3]-lse);
        float4 o1 = make_float4(val[4]-lse, val[5]-lse, val[6]-lse, val[7]-lse);
        *(float4*)(out + (size_t)d * 40 + c8)     = o0;
        *(float4*)(out + (size_t)d * 40 + c8 + 4) = o1;
    }
}

// ---------------- launch ----------------
static inline size_t align_up(size_t v, size_t a) { return (v + a - 1) & ~(a - 1); }

extern "C" void kernel_launch(void* const* d_in, const int* in_sizes, int n_in,
                              void* d_out, int out_size, void* d_ws, size_t ws_size,
                              hipStream_t stream) {
    const float* x  = (const float*)d_in[0];
    const int*   ei = (const int*)d_in[1];
    const float* W1 = (const float*)d_in[2];
    const float* b1 = (const float*)d_in[3];
    const float* W2 = (const float*)d_in[4];
    const float* b2 = (const float*)d_in[5];
    const float* W3 = (const float*)d_in[6];
    const float* b3 = (const float*)d_in[7];
    float* out = (float*)d_out;

    const int n = in_sizes[0] / 128;
    const int e = in_sizes[1] / 2;
    const int* src = ei;
    const int* dst = ei + e;
    const int valn = (((uintptr_t)src & 15) == 0 && ((uintptr_t)dst & 15) == 0) ? 1 : 0;

    const int nbuck = (n + BSIZE - 1) >> BSHIFT;            // 196 for n=100k
    const int nblk  = (e + PASS1_CHUNK - 1) / PASS1_CHUNK;  // 391

    // workspace: dis[n] | rowptr[n+1] | bcnt[1k] |
    //            hmat[nblk*nbuck] | bmat[nblk*nbuck] | csr[e] |
    //            hsb (n*64 u16) | hs2b (n*64 u16)
    // pairs u32[e] aliases hsb (consumed in sort2 before gemm1 writes hsb).
    char* base = (char*)d_ws;
    size_t off = 0;
    float* dis = (float*)(base + off);    off = align_up(off + (size_t)n * 4, 256);
    int* rowptr = (int*)(base + off);     off = align_up(off + (size_t)(n + 1) * 4, 256);
    int* bcnt = (int*)(base + off);       off = align_up(off + 1024 * 4, 256);
    int* hmat = (int*)(base + off);       off = align_up(off + (size_t)nblk * nbuck * 4, 256);
    int* bmat = (int*)(base + off);       off = align_up(off + (size_t)nblk * nbuck * 4, 256);
    int* csr = (int*)(base + off);        off = align_up(off + (size_t)e * 4, 256);
    u16* hsb = (u16*)(base + off);        off = align_up(off + (size_t)n * 64 * 2, 256);
    u16* hs2b = (u16*)(base + off);       off = align_up(off + (size_t)n * 64 * 2, 256);
    u32* pairs = (u32*)hsb;

    const int gb_rows = (n + 63) / 64;
    const int gb_agg  = (n + 31) / 32;

    // CSR build (deterministic, no global atomics; 4 kernels)
    hist_kernel<<<nblk, S1THREADS, 0, stream>>>(dst, hmat, e, nbuck, valn);
    colscan_kernel<<<nbuck, THREADS, 0, stream>>>(hmat, bmat, bcnt, nblk, nbuck);
    scatter_kernel<<<nblk, S1THREADS, 0, stream>>>(src, dst, bmat, bcnt, pairs, e, nbuck, valn);
    sort2_kernel<<<nbuck, S1THREADS, 0, stream>>>(bcnt, pairs, rowptr, dis, csr, n, e, nbuck);

    // layer 1: x @ W1 -> hsb (hs1, bf16)
    mfma_gemm_kernel<128, 64, 64><<<gb_rows, THREADS, 0, stream>>>(x, W1, dis, hsb, n);

    // layer 2 fused: gather-agg(hs1) + swish(+b1) + @W2 -> hs2b (hs2)
    fused_agg_gemm_kernel<64, 64><<<gb_rows, THREADS, 0, stream>>>(
        rowptr, csr, hsb, W2, b1, dis, hs2b, n);

    // layer 3 fused: gather-agg(hs2) + swish(+b2) + @W3 -> hsb (hs3, stride 40)
    fused_agg_gemm_kernel<40, 40><<<gb_rows, THREADS, 0, stream>>>(
        rowptr, csr, hs2b, W3, b2, dis, hsb, n);

    // final: gather-agg(hs3) + bias + log_softmax -> out
    agg40_lsm_kernel<<<gb_agg, THREADS, 0, stream>>>(rowptr, csr, hsb, dis, b3, out, n);
}